// Round 6
// baseline (108.275 us; speedup 1.0000x reference)
//
#include <hip/hip_runtime.h>
#include <hip/hip_bf16.h>
#include <hip/hip_fp8.h>

// SimCLR NT-Xent loss on MI355X.
// loss = -(1/2B) sum_t [ 10*G[t,j0(t)] - (10 + log sum_{j!=t} exp(10*G[t,j]-10)) ]
// where G = M M^T, M = l2norm rows of [z_i; z_j], j0 = (t%B==0) ? 1 : 0.
// Round 6: MX-scaled fp8 MFMA (mfma_scale_f32_32x32x64_f8f6f4, scale=1.0)
// -- the only path to the ~4.7 PF fp8 rate; halves the MFMA-issue floor.
// Staging identical to round 5 (fp8, K-chunk 128 B, global_load_lds 16B,
// XOR-swizzled LDS, XCD-banded tile order, relaxed atomics only).

#define BB 4096      // batch B
#define DD 512       // feature dim (bytes per row in fp8)
#define NN 8192      // 2B rows of G
#define TILE 128     // block tile (rows x cols)
#define KB 128       // K bytes (=elements) staged per LDS chunk
#define NBLK 2080    // 64*65/2 upper-triangle block tiles

typedef __attribute__((ext_vector_type(4)))  int   int4v;   // 16 B
typedef __attribute__((ext_vector_type(8)))  int   int8v;   // 32 B (8 VGPR)
typedef __attribute__((ext_vector_type(16))) float f32x16;

#define AS1 __attribute__((address_space(1)))
#define AS3 __attribute__((address_space(3)))
static __device__ __forceinline__ void gload_lds16(const void* g, void* l) {
    __builtin_amdgcn_global_load_lds((const AS1 void*)g, (AS3 void*)l, 16, 0, 0);
}

// ---------------- kernel 1: L2-normalize rows, cast to fp8; zero rowsum ----
// One wave per row: 64 lanes x 8 f32, shuffle reduce, no LDS/barrier.
__global__ __launch_bounds__(256)
void normalize_kernel(const float* __restrict__ zi, const float* __restrict__ zj,
                      unsigned char* __restrict__ M, float* __restrict__ rowsum) {
    const int wave = threadIdx.x >> 6;
    const int lane = threadIdx.x & 63;
    const int row  = blockIdx.x * 4 + wave;      // 2048 blocks * 4 rows
    if (threadIdx.x < 4) rowsum[blockIdx.x * 4 + threadIdx.x] = 0.f;
    const float* src = (row < BB) ? (zi + (size_t)row * DD)
                                  : (zj + (size_t)(row - BB) * DD);
    float4 v0 = ((const float4*)src)[lane * 2 + 0];
    float4 v1 = ((const float4*)src)[lane * 2 + 1];
    float ss = v0.x*v0.x + v0.y*v0.y + v0.z*v0.z + v0.w*v0.w
             + v1.x*v1.x + v1.y*v1.y + v1.z*v1.z + v1.w*v1.w;
    #pragma unroll
    for (int off = 1; off <= 32; off <<= 1) ss += __shfl_xor(ss, off);
    const float inv = rsqrtf(ss);
    const float vals[8] = {v0.x*inv, v0.y*inv, v0.z*inv, v0.w*inv,
                           v1.x*inv, v1.y*inv, v1.z*inv, v1.w*inv};
    union { long u; unsigned char b[8]; } pk;
    #pragma unroll
    for (int j = 0; j < 8; ++j)
        pk.b[j] = __hip_cvt_float_to_fp8(vals[j], __HIP_SATFINITE, __HIP_E4M3);
    ((long*)(M + (size_t)row * DD))[lane] = pk.u;
}

// ---------------- kernel 2: Gram tile + exp row/col sums -------------------
// 2080 blocks, one upper-triangle 128x128 tile each (by >= bx).
// Wave w: rows wr=(w>>1)*64, cols wc=(w&1)*64; each wave = 2x2 of 32x32 MFMA.
// LDS: row-major 128 rows x 128 B, XOR-swizzled 16B granules
//   granule q holds (row=q>>3, g=(q&7)^((q>>3)&7)); gather side inverts the
//   swizzle so global_load_lds's lane-linear dest constraint is satisfied.
__global__ __launch_bounds__(256, 3)
void gram_lse_kernel(const unsigned char* __restrict__ Mg,
                     float* __restrict__ rowsum, float* __restrict__ targets) {
    __shared__ __align__(16) char As[TILE * KB];   // 16 KB
    __shared__ __align__(16) char Bs[TILE * KB];   // 16 KB

    // XCD-banded order: dispatch d -> band d%8 (one XCD), 260 tiles per band.
    const int d = blockIdx.x;
    const int p = (d & 7) * 260 + (d >> 3);
    // triangular decode: p -> (bx, by) with by >= bx
    int by = (int)((sqrtf(8.0f * (float)p + 1.0f) - 1.0f) * 0.5f);
    while ((by + 1) * (by + 2) / 2 <= p) ++by;
    while (by * (by + 1) / 2 > p) --by;
    const int bx = p - by * (by + 1) / 2;

    const int rowBase = bx * TILE;
    const int colBase = by * TILE;
    const bool diag = (bx == by);
    const int tid  = threadIdx.x;
    const int wave = tid >> 6;
    const int lane = tid & 63;
    const int wr = (wave >> 1) * 64;
    const int wc = (wave & 1) * 64;
    const int l31 = lane & 31;
    const int hi2 = lane >> 5;          // k-half selector / row offset in C
    const int r7  = l31 & 7;

    // staging gather pattern (constant per thread across issues & k0):
    const int sg  = (tid & 7) ^ ((tid >> 3) & 7);   // source granule within row
    const int sr0 = tid >> 3;                        // source row base (+32/issue)
    const unsigned char* gA0 = Mg + (size_t)(rowBase + sr0) * DD + sg * 16;
    const unsigned char* gB0 = Mg + (size_t)(colBase + sr0) * DD + sg * 16;
    char* lA0 = As + tid * 16;                       // granule q = tid (+256/issue)
    char* lB0 = Bs + tid * 16;

    // fragment addressing: A/B operand layout for 32x32x64 f8:
    //   m(n) = lane&31, k = (lane>>5)*32 + j (32 consecutive bytes)
    // row = w*+mi*32+l31, byte range [ks*64 + hi2*32, +32) -> granules
    //   gb = ks*4 + hi2*2 + {0,1}, swizzled by ^(row&7) = ^r7.
    const int arow0 = (wr + l31) * KB;
    const int brow0 = (wc + l31) * KB;
    const char* BsP = diag ? As : Bs;

    f32x16 acc[2][2] = {};

    for (int k0 = 0; k0 < DD; k0 += KB) {
        __syncthreads();   // previous-iteration LDS reads done
        #pragma unroll
        for (int i = 0; i < 4; ++i)
            gload_lds16(gA0 + k0 + (size_t)i * 32 * DD, lA0 + i * 4096);
        if (!diag) {
            #pragma unroll
            for (int i = 0; i < 4; ++i)
                gload_lds16(gB0 + k0 + (size_t)i * 32 * DD, lB0 + i * 4096);
        }
        __syncthreads();   // drains vmcnt(0): staging complete
        #pragma unroll
        for (int ks = 0; ks < 2; ++ks) {
            const int gb = ks * 4 + hi2 * 2;
            int8v a[2], b[2];
            #pragma unroll
            for (int mi = 0; mi < 2; ++mi) {
                int4v lo = *(const int4v*)(As + arow0 + mi * 4096 + (((gb + 0) ^ r7) << 4));
                int4v hi = *(const int4v*)(As + arow0 + mi * 4096 + (((gb + 1) ^ r7) << 4));
                a[mi] = __builtin_shufflevector(lo, hi, 0, 1, 2, 3, 4, 5, 6, 7);
            }
            #pragma unroll
            for (int ni = 0; ni < 2; ++ni) {
                int4v lo = *(const int4v*)(BsP + brow0 + ni * 4096 + (((gb + 0) ^ r7) << 4));
                int4v hi = *(const int4v*)(BsP + brow0 + ni * 4096 + (((gb + 1) ^ r7) << 4));
                b[ni] = __builtin_shufflevector(lo, hi, 0, 1, 2, 3, 4, 5, 6, 7);
            }
            #pragma unroll
            for (int mi = 0; mi < 2; ++mi)
                #pragma unroll
                for (int ni = 0; ni < 2; ++ni)
                    acc[mi][ni] = __builtin_amdgcn_mfma_scale_f32_32x32x64_f8f6f4(
                        a[mi], b[ni], acc[mi][ni],
                        0, 0,          // fmtA=fp8, fmtB=fp8
                        0, 127,        // scaleA sel=0, E8M0 127 = 1.0
                        0, 127);       // scaleB sel=0, 1.0
        }
    }

    // ---- epilogue ----
    // 32x32 C/D layout: col = lane&31, row = (reg&3) + 8*(reg>>2) + 4*(lane>>5)
    // [verified m74/m101; dtype-independent m121-m128]
    float cs[2] = {0.f, 0.f};              // column partials (off-diag tiles)
    #pragma unroll
    for (int mi = 0; mi < 2; ++mi) {
        float rs[16];
        #pragma unroll
        for (int r = 0; r < 16; ++r) rs[r] = 0.f;
        #pragma unroll
        for (int ni = 0; ni < 2; ++ni) {
            const int gcol = colBase + wc + ni * 32 + l31;
            #pragma unroll
            for (int r = 0; r < 16; ++r) {
                const int grow = rowBase + wr + mi * 32 + (r & 3) + 8 * (r >> 2) + 4 * hi2;
                float logit = 10.f * acc[mi][ni][r];
                float e = __expf(logit - 10.f);
                if (grow == gcol) e = 0.f;     // exclude diagonal exactly
                rs[r] += e;
                cs[ni] += e;
                // targets: rows 0/1 of G give 10*G[t, j0] transposed.
                // Only bx==0 blocks write; disjoint col ranges -> plain store.
                if (rowBase == 0 && grow < 2) {
                    const int j0 = ((gcol & (BB - 1)) == 0) ? 1 : 0;
                    if (grow == j0) targets[gcol] = logit;
                }
            }
        }
        #pragma unroll
        for (int m = 1; m <= 16; m <<= 1)
            #pragma unroll
            for (int r = 0; r < 16; ++r)
                rs[r] += __shfl_xor(rs[r], m);
        if (l31 == 0) {
            #pragma unroll
            for (int r = 0; r < 16; ++r)
                atomicAdd(&rowsum[rowBase + wr + mi * 32 + (r & 3) + 8 * (r >> 2) + 4 * hi2],
                          rs[r]);
        }
    }
    if (!diag) {
        #pragma unroll
        for (int ni = 0; ni < 2; ++ni) {
            cs[ni] += __shfl_xor(cs[ni], 32);
            if (hi2 == 0)
                atomicAdd(&rowsum[colBase + wc + ni * 32 + l31], cs[ni]);
        }
    }
}

// ---------------- kernel 3: final scalar reduction -------------------------
__global__ __launch_bounds__(1024)
void finalize_kernel(const float* __restrict__ rowsum,
                     const float* __restrict__ targets, float* __restrict__ out) {
    const int tid = threadIdx.x;
    float s = 0.f;
    #pragma unroll
    for (int t = tid; t < NN; t += 1024)
        s += targets[t] - 10.f - __logf(rowsum[t]);
    #pragma unroll
    for (int off = 1; off <= 32; off <<= 1) s += __shfl_xor(s, off);
    __shared__ float red[16];
    if ((tid & 63) == 0) red[tid >> 6] = s;
    __syncthreads();
    if (tid == 0) {
        float t = 0.f;
        #pragma unroll
        for (int i = 0; i < 16; ++i) t += red[i];
        out[0] = -t / (float)NN;
    }
}

extern "C" void kernel_launch(void* const* d_in, const int* in_sizes, int n_in,
                              void* d_out, int out_size, void* d_ws, size_t ws_size,
                              hipStream_t stream) {
    const float* zi = (const float*)d_in[0];
    const float* zj = (const float*)d_in[1];

    unsigned char* M = (unsigned char*)d_ws;                         // 4 MB fp8
    float* rowsum  = (float*)((char*)d_ws + (size_t)NN * DD);        // 32 KB
    float* targets = rowsum + NN;                                    // 32 KB
    float* out = (float*)d_out;

    normalize_kernel<<<NN / 4, 256, 0, stream>>>(zi, zj, M, rowsum);
    gram_lse_kernel<<<NBLK, 256, 0, stream>>>(M, rowsum, targets);
    finalize_kernel<<<1, 1024, 0, stream>>>(rowsum, targets, out);
}